// Round 4
// baseline (219.002 us; speedup 1.0000x reference)
//
#include <hip/hip_runtime.h>
#include <hip/hip_fp16.h>
#include <math.h>

#define BB 128
#define FF 256
#define NN 2000

typedef float f32x4 __attribute__((ext_vector_type(4)));
union H8 { f32x4 v; __half2 h[4]; };

// -------- K1: convert x -> fp16 AND row max (one wave per row, 16B ld/st) --------
__global__ __launch_bounds__(256) void k_convmax(const float* __restrict__ x,
                                                 __half* __restrict__ xh,
                                                 float* __restrict__ glb) {
    int row  = (blockIdx.x << 2) | (threadIdx.x >> 6);
    int lane = threadIdx.x & 63;
    const f32x4* src = (const f32x4*)(x + (size_t)row * NN);
    f32x4*       dst = (f32x4*)(xh + (size_t)row * NN);
    float m = -INFINITY;
    for (int i = lane; i < 250; i += 64) {
        f32x4 a = __builtin_nontemporal_load(src + 2 * i);
        f32x4 b = __builtin_nontemporal_load(src + 2 * i + 1);
        m = fmaxf(m, fmaxf(fmaxf(a.x, a.y), fmaxf(a.z, a.w)));
        m = fmaxf(m, fmaxf(fmaxf(b.x, b.y), fmaxf(b.z, b.w)));
        H8 o;
        o.h[0] = __floats2half2_rn(a.x, a.y);
        o.h[1] = __floats2half2_rn(a.z, a.w);
        o.h[2] = __floats2half2_rn(b.x, b.y);
        o.h[3] = __floats2half2_rn(b.z, b.w);
        dst[i] = o.v;
    }
#pragma unroll
    for (int off = 32; off; off >>= 1) m = fmaxf(m, __shfl_xor(m, off));
    if (!lane) glb[row] = m;
}

// -------- K2: per-batch dense prep -> cK[b,f], cK0[b] --------
__global__ __launch_bounds__(256) void k_prep(
    const float* __restrict__ x, const int* __restrict__ lc,
    const float* __restrict__ glb,
    const float* __restrict__ Wg, const float* __restrict__ bg,
    const float* __restrict__ Wnode, const float* __restrict__ bnode,
    const float* __restrict__ Wlc, const float* __restrict__ blc,
    float* __restrict__ cK, float* __restrict__ cK0)
{
    int b = blockIdx.x;
    int f = threadIdx.x;
    __shared__ float s_glb[FF], s_ctx[2 * FF], s_cQ[FF], s_red[FF];
    const float* xb = x + (size_t)b * FF * NN;
    s_glb[f] = glb[b * FF + f];
    int l0 = lc[2 * b], l1 = lc[2 * b + 1];
    s_ctx[f]      = xb[(size_t)f * NN + l0];
    s_ctx[FF + f] = xb[(size_t)f * NN + l1];
    __syncthreads();
    const float* wg = Wg + (size_t)f * FF;
    float q0 = 0, q1 = 0, q2 = 0, q3 = 0;
    for (int j = 0; j < FF; j += 4) {
        q0 = fmaf(wg[j],     s_glb[j],     q0);
        q1 = fmaf(wg[j + 1], s_glb[j + 1], q1);
        q2 = fmaf(wg[j + 2], s_glb[j + 2], q2);
        q3 = fmaf(wg[j + 3], s_glb[j + 3], q3);
    }
    const float* wl = Wlc + (size_t)f * 2 * FF;
    for (int j = 0; j < 2 * FF; j += 4) {
        q0 = fmaf(wl[j],     s_ctx[j],     q0);
        q1 = fmaf(wl[j + 1], s_ctx[j + 1], q1);
        q2 = fmaf(wl[j + 2], s_ctx[j + 2], q2);
        q3 = fmaf(wl[j + 3], s_ctx[j + 3], q3);
    }
    float cq = bg[f] + blc[f] + ((q0 + q1) + (q2 + q3));
    s_cQ[f]  = cq;
    s_red[f] = cq * bnode[f];
    __syncthreads();
    float c0 = 0, c1 = 0;
    for (int g = 0; g < FF; g += 2) {
        c0 = fmaf(s_cQ[g],     Wnode[(size_t)g * FF + f],       c0);
        c1 = fmaf(s_cQ[g + 1], Wnode[(size_t)(g + 1) * FF + f], c1);
    }
    cK[b * FF + f] = c0 + c1;
    for (int s = 128; s > 0; s >>= 1) {
        if (f < s) s_red[f] += s_red[f + s];
        __syncthreads();
    }
    if (f == 0) cK0[b] = s_red[0];
}

// -------- K3: fused ucj + stripe-softmax + stripe-ypool (4 blocks/batch) --------
__global__ __launch_bounds__(256) void k_attn(
    const __half* __restrict__ xh,
    const float* __restrict__ cK, const float* __restrict__ cK0,
    float* __restrict__ y_part, float* __restrict__ m_part,
    float* __restrict__ s_part)
{
    int b = blockIdx.x >> 2, s = blockIdx.x & 3;
    int tid = threadIdx.x, w = tid >> 6, lane = tid & 63;
    __shared__ float s_cK[FF];
    __shared__ float s_acc[4][512];
    __shared__ float s_p[512];
    __shared__ float s_red[8];
    s_cK[tid] = cK[b * FF + tid];
    __syncthreads();

    int n0 = s << 9;
    int nbase = n0 + (lane << 3);
    bool valid = nbase < NN;

    // ---- pass 1: u partials over this wave's 64 f-rows ----
    float a0 = 0, a1 = 0, a2 = 0, a3 = 0, a4 = 0, a5 = 0, a6 = 0, a7 = 0;
    if (valid) {
        const __half* rp = xh + (size_t)(b * FF + (w << 6)) * NN + nbase;
#pragma unroll 4
        for (int fi = 0; fi < 64; ++fi) {
            H8 hv; hv.v = *(const f32x4*)rp;
            rp += NN;
            float c = s_cK[(w << 6) + fi];
            float2 q0 = __half22float2(hv.h[0]);
            float2 q1 = __half22float2(hv.h[1]);
            float2 q2 = __half22float2(hv.h[2]);
            float2 q3 = __half22float2(hv.h[3]);
            a0 = fmaf(c, q0.x, a0); a1 = fmaf(c, q0.y, a1);
            a2 = fmaf(c, q1.x, a2); a3 = fmaf(c, q1.y, a3);
            a4 = fmaf(c, q2.x, a4); a5 = fmaf(c, q2.y, a5);
            a6 = fmaf(c, q3.x, a6); a7 = fmaf(c, q3.y, a7);
        }
    }
    int cb = lane << 3;
    s_acc[w][cb + 0] = a0; s_acc[w][cb + 1] = a1;
    s_acc[w][cb + 2] = a2; s_acc[w][cb + 3] = a3;
    s_acc[w][cb + 4] = a4; s_acc[w][cb + 5] = a5;
    s_acc[w][cb + 6] = a6; s_acc[w][cb + 7] = a7;
    __syncthreads();

    // ---- stripe softmax (unnormalized): m_i, S_i, p = exp(u - m_i) ----
    const float scale = 0.0625f;
    float k0 = cK0[b];
    float uu0, uu1;
    {
        int c0 = tid, c1 = tid + 256;
        float t0 = s_acc[0][c0] + s_acc[1][c0] + s_acc[2][c0] + s_acc[3][c0];
        float t1 = s_acc[0][c1] + s_acc[1][c1] + s_acc[2][c1] + s_acc[3][c1];
        uu0 = (n0 + c0 < NN) ? (t0 + k0) * scale : -INFINITY;
        uu1 = (n0 + c1 < NN) ? (t1 + k0) * scale : -INFINITY;
    }
    float m = fmaxf(uu0, uu1);
#pragma unroll
    for (int off = 32; off; off >>= 1) m = fmaxf(m, __shfl_xor(m, off));
    if (!lane) s_red[w] = m;
    __syncthreads();
    float M = fmaxf(fmaxf(s_red[0], s_red[1]), fmaxf(s_red[2], s_red[3]));
    float e0 = (uu0 > -INFINITY) ? __expf(uu0 - M) : 0.f;
    float e1 = (uu1 > -INFINITY) ? __expf(uu1 - M) : 0.f;
    s_p[tid]       = e0;
    s_p[tid + 256] = e1;
    float ss = e0 + e1;
#pragma unroll
    for (int off = 32; off; off >>= 1) ss += __shfl_xor(ss, off);
    if (!lane) s_red[4 + w] = ss;
    __syncthreads();
    if (!tid) {
        m_part[(b << 2) + s] = M;
        s_part[(b << 2) + s] = s_red[4] + s_red[5] + s_red[6] + s_red[7];
    }

    // ---- pass 2: y_part[f] = sum_c p[c]*x[f,c]  (tile re-read from L2/L3) ----
    float p0 = 0, p1 = 0, p2 = 0, p3 = 0, p4 = 0, p5 = 0, p6 = 0, p7 = 0;
    if (valid) {
        float4 pa = *(const float4*)&s_p[cb];
        float4 pc = *(const float4*)&s_p[cb + 4];
        p0 = pa.x; p1 = pa.y; p2 = pa.z; p3 = pa.w;
        p4 = pc.x; p5 = pc.y; p6 = pc.z; p7 = pc.w;
    }
    const __half* rp2 = xh + (size_t)(b * FF + (w << 6)) * NN + nbase;
    float* yp = y_part + (size_t)((b << 2) + s) * FF + (w << 6);
#pragma unroll 2
    for (int fi = 0; fi < 64; ++fi) {
        float acc = 0.f;
        if (valid) {
            H8 hv; hv.v = *(const f32x4*)rp2;
            float2 q0 = __half22float2(hv.h[0]);
            float2 q1 = __half22float2(hv.h[1]);
            float2 q2 = __half22float2(hv.h[2]);
            float2 q3 = __half22float2(hv.h[3]);
            acc = fmaf(p0, q0.x, acc); acc = fmaf(p1, q0.y, acc);
            acc = fmaf(p2, q1.x, acc); acc = fmaf(p3, q1.y, acc);
            acc = fmaf(p4, q2.x, acc); acc = fmaf(p5, q2.y, acc);
            acc = fmaf(p6, q3.x, acc); acc = fmaf(p7, q3.y, acc);
        }
        rp2 += NN;
#pragma unroll
        for (int off = 32; off; off >>= 1) acc += __shfl_xor(acc, off);
        if (!lane) yp[fi] = acc;
    }
}

// -------- K4: combine partials -> y -> dense chain -> logits + tanh --------
__global__ __launch_bounds__(256) void k_final(
    const __half* __restrict__ xh,
    const float* __restrict__ y_part, const float* __restrict__ m_part,
    const float* __restrict__ s_part,
    const float* __restrict__ Wnode, const float* __restrict__ bnode,
    const float* __restrict__ Wproj, const float* __restrict__ bproj,
    float* __restrict__ out)
{
    int b = blockIdx.x >> 2, s = blockIdx.x & 3;
    int tid = threadIdx.x, w = tid >> 6, lane = tid & 63;
    __shared__ float s_y[FF], s_v[FF], s_cL[FF];
    __shared__ float s_acc[4][512];
    __shared__ float s_red[8];

    // combine stripe partials
    float m0 = m_part[(b << 2)],     m1 = m_part[(b << 2) + 1];
    float m2 = m_part[(b << 2) + 2], m3 = m_part[(b << 2) + 3];
    float M = fmaxf(fmaxf(m0, m1), fmaxf(m2, m3));
    float w0 = __expf(m0 - M), w1 = __expf(m1 - M);
    float w2 = __expf(m2 - M), w3 = __expf(m3 - M);
    float S = s_part[(b << 2)] * w0 + s_part[(b << 2) + 1] * w1 +
              s_part[(b << 2) + 2] * w2 + s_part[(b << 2) + 3] * w3;
    float invS = 1.0f / S;
    const float* yp = y_part + ((size_t)b << 2) * FF;
    s_y[tid] = (yp[tid] * w0 + yp[FF + tid] * w1 +
                yp[2 * FF + tid] * w2 + yp[3 * FF + tid] * w3) * invS;
    __syncthreads();

    // dense chain (redundant per block, cheap)
    const float* wv = Wnode + (size_t)(FF + tid) * FF;
    float a0 = 0, a1 = 0, a2 = 0, a3 = 0;
    for (int j = 0; j < FF; j += 4) {
        a0 = fmaf(wv[j],     s_y[j],     a0);
        a1 = fmaf(wv[j + 1], s_y[j + 1], a1);
        a2 = fmaf(wv[j + 2], s_y[j + 2], a2);
        a3 = fmaf(wv[j + 3], s_y[j + 3], a3);
    }
    s_v[tid] = bnode[FF + tid] + ((a0 + a1) + (a2 + a3));
    __syncthreads();
    const float* wp = Wproj + (size_t)tid * FF;
    a0 = 0; a1 = 0; a2 = 0; a3 = 0;
    for (int j = 0; j < FF; j += 4) {
        a0 = fmaf(wp[j],     s_v[j],     a0);
        a1 = fmaf(wp[j + 1], s_v[j + 1], a1);
        a2 = fmaf(wp[j + 2], s_v[j + 2], a2);
        a3 = fmaf(wp[j + 3], s_v[j + 3], a3);
    }
    float nc2 = bproj[tid] + ((a0 + a1) + (a2 + a3));
    __syncthreads();
    s_v[tid] = nc2;
    __syncthreads();
    float c0 = 0, c1 = 0;
    for (int g = 0; g < FF; g += 2) {
        c0 = fmaf(s_v[g],     Wnode[(size_t)(2 * FF + g) * FF + tid],     c0);
        c1 = fmaf(s_v[g + 1], Wnode[(size_t)(2 * FF + g + 1) * FF + tid], c1);
    }
    s_cL[tid] = c0 + c1;
    float t = nc2 * bnode[2 * FF + tid];
#pragma unroll
    for (int off = 32; off; off >>= 1) t += __shfl_xor(t, off);
    if (!lane) s_red[w] = t;
    __syncthreads();
    float cl0 = s_red[0] + s_red[1] + s_red[2] + s_red[3];

    // logits stream for this stripe
    int n0 = s << 9;
    int nbase = n0 + (lane << 3);
    bool valid = nbase < NN;
    float b0 = 0, b1 = 0, b2 = 0, b3 = 0, b4 = 0, b5 = 0, b6 = 0, b7 = 0;
    if (valid) {
        const __half* rp = xh + (size_t)(b * FF + (w << 6)) * NN + nbase;
#pragma unroll 4
        for (int fi = 0; fi < 64; ++fi) {
            H8 hv; hv.v = *(const f32x4*)rp;
            rp += NN;
            float c = s_cL[(w << 6) + fi];
            float2 q0 = __half22float2(hv.h[0]);
            float2 q1 = __half22float2(hv.h[1]);
            float2 q2 = __half22float2(hv.h[2]);
            float2 q3 = __half22float2(hv.h[3]);
            b0 = fmaf(c, q0.x, b0); b1 = fmaf(c, q0.y, b1);
            b2 = fmaf(c, q1.x, b2); b3 = fmaf(c, q1.y, b3);
            b4 = fmaf(c, q2.x, b4); b5 = fmaf(c, q2.y, b5);
            b6 = fmaf(c, q3.x, b6); b7 = fmaf(c, q3.y, b7);
        }
    }
    int cb = lane << 3;
    s_acc[w][cb + 0] = b0; s_acc[w][cb + 1] = b1;
    s_acc[w][cb + 2] = b2; s_acc[w][cb + 3] = b3;
    s_acc[w][cb + 4] = b4; s_acc[w][cb + 5] = b5;
    s_acc[w][cb + 6] = b6; s_acc[w][cb + 7] = b7;
    __syncthreads();
    const float scale = 0.0625f;
#pragma unroll
    for (int j = 0; j < 2; ++j) {
        int c = tid + (j << 8);
        int n = n0 + c;
        if (n < NN) {
            float l = (s_acc[0][c] + s_acc[1][c] + s_acc[2][c] + s_acc[3][c] + cl0) * scale;
            out[(size_t)b * NN + n] = tanhf(l) * 10.f;
        }
    }
}

extern "C" void kernel_launch(void* const* d_in, const int* in_sizes, int n_in,
                              void* d_out, int out_size, void* d_ws, size_t ws_size,
                              hipStream_t stream) {
    const float* x     = (const float*)d_in[0];
    const int*   lc    = (const int*)d_in[1];
    const float* Wg    = (const float*)d_in[2];
    const float* bg    = (const float*)d_in[3];
    const float* Wnode = (const float*)d_in[4];
    const float* bnode = (const float*)d_in[5];
    const float* Wlc   = (const float*)d_in[6];
    const float* blc   = (const float*)d_in[7];
    const float* Wproj = (const float*)d_in[8];
    const float* bproj = (const float*)d_in[9];
    float* out = (float*)d_out;

    float* ws     = (float*)d_ws;
    float* glb    = ws + 0;        // B*F
    float* cK     = ws + 40960;    // B*F
    float* cK0    = ws + 81920;    // B
    float* m_part = ws + 82432;    // B*4
    float* s_part = ws + 83456;    // B*4
    float* y_part = ws + 84480;    // B*4*F = 131072
    __half* xh    = (__half*)(ws + (1 << 20));  // 131 MB at 4 MB offset

    k_convmax<<<BB * FF / 4, 256, 0, stream>>>(x, xh, glb);
    k_prep   <<<BB, 256, 0, stream>>>(x, lc, glb, Wg, bg, Wnode, bnode, Wlc, blc, cK, cK0);
    k_attn   <<<BB * 4, 256, 0, stream>>>(xh, cK, cK0, y_part, m_part, s_part);
    k_final  <<<BB * 4, 256, 0, stream>>>(xh, y_part, m_part, s_part, Wnode, bnode, Wproj, bproj, out);
}

// Round 5
// 201.891 us; speedup vs baseline: 1.0848x; 1.0848x over previous
//
#include <hip/hip_runtime.h>
#include <hip/hip_fp16.h>
#include <math.h>

#define BB 128
#define FF 256
#define NN 2000

typedef float f32x4 __attribute__((ext_vector_type(4)));
union H8 { f32x4 v; __half2 h[4]; };

// -------- K1: convert x -> fp16 AND row max (one wave per row, 16B ld/st) --------
__global__ __launch_bounds__(256) void k_convmax(const float* __restrict__ x,
                                                 __half* __restrict__ xh,
                                                 float* __restrict__ glb) {
    int row  = (blockIdx.x << 2) | (threadIdx.x >> 6);
    int lane = threadIdx.x & 63;
    const f32x4* src = (const f32x4*)(x + (size_t)row * NN);
    f32x4*       dst = (f32x4*)(xh + (size_t)row * NN);
    float m = -INFINITY;
    for (int i = lane; i < 250; i += 64) {
        f32x4 a = __builtin_nontemporal_load(src + 2 * i);
        f32x4 b = __builtin_nontemporal_load(src + 2 * i + 1);
        m = fmaxf(m, fmaxf(fmaxf(a.x, a.y), fmaxf(a.z, a.w)));
        m = fmaxf(m, fmaxf(fmaxf(b.x, b.y), fmaxf(b.z, b.w)));
        H8 o;
        o.h[0] = __floats2half2_rn(a.x, a.y);
        o.h[1] = __floats2half2_rn(a.z, a.w);
        o.h[2] = __floats2half2_rn(b.x, b.y);
        o.h[3] = __floats2half2_rn(b.z, b.w);
        dst[i] = o.v;
    }
#pragma unroll
    for (int off = 32; off; off >>= 1) m = fmaxf(m, __shfl_xor(m, off));
    if (!lane) glb[row] = m;
}

// -------- K2: per-batch dense prep -> cK[b,f], cK0[b] --------
__global__ __launch_bounds__(256) void k_prep(
    const float* __restrict__ x, const int* __restrict__ lc,
    const float* __restrict__ glb,
    const float* __restrict__ Wg, const float* __restrict__ bg,
    const float* __restrict__ Wnode, const float* __restrict__ bnode,
    const float* __restrict__ Wlc, const float* __restrict__ blc,
    float* __restrict__ cK, float* __restrict__ cK0)
{
    int b = blockIdx.x;
    int f = threadIdx.x;
    __shared__ float s_glb[FF], s_ctx[2 * FF], s_cQ[FF], s_red[FF];
    const float* xb = x + (size_t)b * FF * NN;
    s_glb[f] = glb[b * FF + f];
    int l0 = lc[2 * b], l1 = lc[2 * b + 1];
    s_ctx[f]      = xb[(size_t)f * NN + l0];
    s_ctx[FF + f] = xb[(size_t)f * NN + l1];
    __syncthreads();
    const float* wg = Wg + (size_t)f * FF;
    float q0 = 0, q1 = 0, q2 = 0, q3 = 0;
    for (int j = 0; j < FF; j += 4) {
        q0 = fmaf(wg[j],     s_glb[j],     q0);
        q1 = fmaf(wg[j + 1], s_glb[j + 1], q1);
        q2 = fmaf(wg[j + 2], s_glb[j + 2], q2);
        q3 = fmaf(wg[j + 3], s_glb[j + 3], q3);
    }
    const float* wl = Wlc + (size_t)f * 2 * FF;
    for (int j = 0; j < 2 * FF; j += 4) {
        q0 = fmaf(wl[j],     s_ctx[j],     q0);
        q1 = fmaf(wl[j + 1], s_ctx[j + 1], q1);
        q2 = fmaf(wl[j + 2], s_ctx[j + 2], q2);
        q3 = fmaf(wl[j + 3], s_ctx[j + 3], q3);
    }
    float cq = bg[f] + blc[f] + ((q0 + q1) + (q2 + q3));
    s_cQ[f]  = cq;
    s_red[f] = cq * bnode[f];
    __syncthreads();
    float c0 = 0, c1 = 0;
    for (int g = 0; g < FF; g += 2) {
        c0 = fmaf(s_cQ[g],     Wnode[(size_t)g * FF + f],       c0);
        c1 = fmaf(s_cQ[g + 1], Wnode[(size_t)(g + 1) * FF + f], c1);
    }
    cK[b * FF + f] = c0 + c1;
    for (int s = 128; s > 0; s >>= 1) {
        if (f < s) s_red[f] += s_red[f + s];
        __syncthreads();
    }
    if (f == 0) cK0[b] = s_red[0];
}

// -------- K3: fused u + stripe-softmax + stripe-ypool (LDS-transpose reduce) --------
__global__ __launch_bounds__(256) void k_attn(
    const __half* __restrict__ xh,
    const float* __restrict__ cK, const float* __restrict__ cK0,
    float* __restrict__ y_part8, float* __restrict__ m_part,
    float* __restrict__ s_part)
{
    int b = blockIdx.x >> 2, s = blockIdx.x & 3;
    int tid = threadIdx.x, w = tid >> 6, lane = tid & 63;
    __shared__ float s_cK[FF];
    __shared__ float s_buf[4][512];
    __shared__ float s_p[512];
    __shared__ float s_red[8];
    s_cK[tid] = cK[b * FF + tid];
    __syncthreads();

    int n0 = s << 9;
    int nbase = n0 + (lane << 3);
    bool valid = nbase < NN;
    int cb = lane << 3;

    // ---- pass 1: u partials over this wave's 64 f-rows ----
    float a0 = 0, a1 = 0, a2 = 0, a3 = 0, a4 = 0, a5 = 0, a6 = 0, a7 = 0;
    const __half* rp = xh + (size_t)(b * FF + (w << 6)) * NN + nbase;
    if (valid) {
#pragma unroll 4
        for (int fi = 0; fi < 64; ++fi) {
            H8 hv; hv.v = *(const f32x4*)(rp + (size_t)fi * NN);
            float c = s_cK[(w << 6) + fi];
            float2 q0 = __half22float2(hv.h[0]);
            float2 q1 = __half22float2(hv.h[1]);
            float2 q2 = __half22float2(hv.h[2]);
            float2 q3 = __half22float2(hv.h[3]);
            a0 = fmaf(c, q0.x, a0); a1 = fmaf(c, q0.y, a1);
            a2 = fmaf(c, q1.x, a2); a3 = fmaf(c, q1.y, a3);
            a4 = fmaf(c, q2.x, a4); a5 = fmaf(c, q2.y, a5);
            a6 = fmaf(c, q3.x, a6); a7 = fmaf(c, q3.y, a7);
        }
    }
    s_buf[w][cb + 0] = a0; s_buf[w][cb + 1] = a1;
    s_buf[w][cb + 2] = a2; s_buf[w][cb + 3] = a3;
    s_buf[w][cb + 4] = a4; s_buf[w][cb + 5] = a5;
    s_buf[w][cb + 6] = a6; s_buf[w][cb + 7] = a7;
    __syncthreads();

    // ---- stripe softmax (unnormalized): M_i, S_i, p = exp(u - M_i) ----
    const float scale = 0.0625f;
    float k0 = cK0[b];
    float uu0, uu1;
    {
        int c0 = tid, c1 = tid + 256;
        float t0 = s_buf[0][c0] + s_buf[1][c0] + s_buf[2][c0] + s_buf[3][c0];
        float t1 = s_buf[0][c1] + s_buf[1][c1] + s_buf[2][c1] + s_buf[3][c1];
        uu0 = (n0 + c0 < NN) ? (t0 + k0) * scale : -INFINITY;
        uu1 = (n0 + c1 < NN) ? (t1 + k0) * scale : -INFINITY;
    }
    float m = fmaxf(uu0, uu1);
#pragma unroll
    for (int off = 32; off; off >>= 1) m = fmaxf(m, __shfl_xor(m, off));
    if (!lane) s_red[w] = m;
    __syncthreads();
    float M = fmaxf(fmaxf(s_red[0], s_red[1]), fmaxf(s_red[2], s_red[3]));
    float e0 = (uu0 > -INFINITY) ? __expf(uu0 - M) : 0.f;
    float e1 = (uu1 > -INFINITY) ? __expf(uu1 - M) : 0.f;
    float ss = e0 + e1;
#pragma unroll
    for (int off = 32; off; off >>= 1) ss += __shfl_xor(ss, off);
    __syncthreads();               // s_buf reads done; s_p/s_red reuse safe
    s_p[tid]       = e0;
    s_p[tid + 256] = e1;
    if (!lane) s_red[4 + w] = ss;
    __syncthreads();
    if (!tid) {
        m_part[(b << 2) + s] = M;
        s_part[(b << 2) + s] = s_red[4] + s_red[5] + s_red[6] + s_red[7];
    }

    // ---- pass 2: y8 partials, LDS-transpose reduce (no shuffles) ----
    float4 pa = *(const float4*)&s_p[cb];
    float4 pc = *(const float4*)&s_p[cb + 4];
    float* yout = y_part8 + ((size_t)((b << 2) + s)) * 2048 + (w << 9);
    int row = lane >> 3, k = lane & 7;
    for (int g = 0; g < 8; ++g) {
        float part[8];
#pragma unroll
        for (int r = 0; r < 8; ++r) {
            float acc = 0.f;
            if (valid) {
                H8 hv; hv.v = *(const f32x4*)(rp + (size_t)((g << 3) + r) * NN);
                float2 q0 = __half22float2(hv.h[0]);
                float2 q1 = __half22float2(hv.h[1]);
                float2 q2 = __half22float2(hv.h[2]);
                float2 q3 = __half22float2(hv.h[3]);
                acc = fmaf(pa.x, q0.x, acc); acc = fmaf(pa.y, q0.y, acc);
                acc = fmaf(pa.z, q1.x, acc); acc = fmaf(pa.w, q1.y, acc);
                acc = fmaf(pc.x, q2.x, acc); acc = fmaf(pc.y, q2.y, acc);
                acc = fmaf(pc.z, q3.x, acc); acc = fmaf(pc.w, q3.y, acc);
            }
            part[r] = acc;
        }
#pragma unroll
        for (int r = 0; r < 8; ++r) s_buf[w][(r << 6) + lane] = part[r];
        __syncthreads();
        const float* src = &s_buf[w][(row << 6) + (k << 3)];
        float4 aa = *(const float4*)src;
        float4 bb = *(const float4*)(src + 4);
        float sum8 = ((aa.x + aa.y) + (aa.z + aa.w)) + ((bb.x + bb.y) + (bb.z + bb.w));
        yout[(g << 6) + lane] = sum8;
        __syncthreads();
    }
}

// -------- K4: combine stripe partials -> y -> dense chain -> cL, cL0 --------
__global__ __launch_bounds__(256) void k_dense(
    const float* __restrict__ y_part8, const float* __restrict__ m_part,
    const float* __restrict__ s_part,
    const float* __restrict__ Wnode, const float* __restrict__ bnode,
    const float* __restrict__ Wproj, const float* __restrict__ bproj,
    float* __restrict__ cL, float* __restrict__ cL0)
{
    int b = blockIdx.x;
    int f = threadIdx.x;
    int wid = f >> 6, lane = f & 63;
    __shared__ float s_y[FF], s_v[FF], s_red[4];

    float m0 = m_part[(b << 2)],     m1 = m_part[(b << 2) + 1];
    float m2 = m_part[(b << 2) + 2], m3 = m_part[(b << 2) + 3];
    float M = fmaxf(fmaxf(m0, m1), fmaxf(m2, m3));
    float w0 = __expf(m0 - M), w1 = __expf(m1 - M);
    float w2 = __expf(m2 - M), w3 = __expf(m3 - M);
    float S = s_part[(b << 2)] * w0 + s_part[(b << 2) + 1] * w1 +
              s_part[(b << 2) + 2] * w2 + s_part[(b << 2) + 3] * w3;
    float invS = 1.0f / S;
    const float* yb = y_part8 + ((size_t)b << 13);
    float wgt[4] = {w0, w1, w2, w3};
    float acc = 0.f;
#pragma unroll
    for (int s = 0; s < 4; ++s) {
        float4 aa = *(const float4*)(yb + (s << 11) + (f << 3));
        float4 bb = *(const float4*)(yb + (s << 11) + (f << 3) + 4);
        acc += wgt[s] * (((aa.x + aa.y) + (aa.z + aa.w)) + ((bb.x + bb.y) + (bb.z + bb.w)));
    }
    s_y[f] = acc * invS;
    __syncthreads();

    const float* wv = Wnode + (size_t)(FF + f) * FF;
    float a0 = 0, a1 = 0, a2 = 0, a3 = 0;
    for (int j = 0; j < FF; j += 4) {
        a0 = fmaf(wv[j],     s_y[j],     a0);
        a1 = fmaf(wv[j + 1], s_y[j + 1], a1);
        a2 = fmaf(wv[j + 2], s_y[j + 2], a2);
        a3 = fmaf(wv[j + 3], s_y[j + 3], a3);
    }
    s_v[f] = bnode[FF + f] + ((a0 + a1) + (a2 + a3));
    __syncthreads();
    const float* wp = Wproj + (size_t)f * FF;
    a0 = 0; a1 = 0; a2 = 0; a3 = 0;
    for (int j = 0; j < FF; j += 4) {
        a0 = fmaf(wp[j],     s_v[j],     a0);
        a1 = fmaf(wp[j + 1], s_v[j + 1], a1);
        a2 = fmaf(wp[j + 2], s_v[j + 2], a2);
        a3 = fmaf(wp[j + 3], s_v[j + 3], a3);
    }
    float nc2 = bproj[f] + ((a0 + a1) + (a2 + a3));
    __syncthreads();
    s_v[f] = nc2;
    __syncthreads();
    float c0 = 0, c1 = 0;
    for (int g = 0; g < FF; g += 2) {
        c0 = fmaf(s_v[g],     Wnode[(size_t)(2 * FF + g) * FF + f],     c0);
        c1 = fmaf(s_v[g + 1], Wnode[(size_t)(2 * FF + g + 1) * FF + f], c1);
    }
    cL[b * FF + f] = c0 + c1;
    float t = nc2 * bnode[2 * FF + f];
#pragma unroll
    for (int off = 32; off; off >>= 1) t += __shfl_xor(t, off);
    if (!lane) s_red[wid] = t;
    __syncthreads();
    if (!f) cL0[b] = s_red[0] + s_red[1] + s_red[2] + s_red[3];
}

// -------- K5: logits + tanh (4 blocks/batch) --------
__global__ __launch_bounds__(256) void k_logits(const __half* __restrict__ xh,
                                                const float* __restrict__ cL,
                                                const float* __restrict__ cL0,
                                                float* __restrict__ out)
{
    int b = blockIdx.x >> 2, s = blockIdx.x & 3;
    int tid = threadIdx.x, w = tid >> 6, lane = tid & 63;
    __shared__ float s_cL[FF];
    __shared__ float s_acc[4][512];
    s_cL[tid] = cL[b * FF + tid];
    __syncthreads();
    int n0 = s << 9;
    int nbase = n0 + (lane << 3);
    float a0 = 0, a1 = 0, a2 = 0, a3 = 0, a4 = 0, a5 = 0, a6 = 0, a7 = 0;
    if (nbase < NN) {
        const __half* rp = xh + (size_t)(b * FF + (w << 6)) * NN + nbase;
#pragma unroll 4
        for (int fi = 0; fi < 64; ++fi) {
            H8 hv; hv.v = *(const f32x4*)rp;
            rp += NN;
            float c = s_cL[(w << 6) + fi];
            float2 q0 = __half22float2(hv.h[0]);
            float2 q1 = __half22float2(hv.h[1]);
            float2 q2 = __half22float2(hv.h[2]);
            float2 q3 = __half22float2(hv.h[3]);
            a0 = fmaf(c, q0.x, a0); a1 = fmaf(c, q0.y, a1);
            a2 = fmaf(c, q1.x, a2); a3 = fmaf(c, q1.y, a3);
            a4 = fmaf(c, q2.x, a4); a5 = fmaf(c, q2.y, a5);
            a6 = fmaf(c, q3.x, a6); a7 = fmaf(c, q3.y, a7);
        }
    }
    int cb = lane << 3;
    s_acc[w][cb + 0] = a0; s_acc[w][cb + 1] = a1;
    s_acc[w][cb + 2] = a2; s_acc[w][cb + 3] = a3;
    s_acc[w][cb + 4] = a4; s_acc[w][cb + 5] = a5;
    s_acc[w][cb + 6] = a6; s_acc[w][cb + 7] = a7;
    __syncthreads();
    float cl0 = cL0[b];
    const float scale = 0.0625f;
#pragma unroll
    for (int j = 0; j < 2; ++j) {
        int c = tid + (j << 8);
        int n = n0 + c;
        if (n < NN) {
            float l = (s_acc[0][c] + s_acc[1][c] + s_acc[2][c] + s_acc[3][c] + cl0) * scale;
            out[(size_t)b * NN + n] = tanhf(l) * 10.f;
        }
    }
}

extern "C" void kernel_launch(void* const* d_in, const int* in_sizes, int n_in,
                              void* d_out, int out_size, void* d_ws, size_t ws_size,
                              hipStream_t stream) {
    const float* x     = (const float*)d_in[0];
    const int*   lc    = (const int*)d_in[1];
    const float* Wg    = (const float*)d_in[2];
    const float* bg    = (const float*)d_in[3];
    const float* Wnode = (const float*)d_in[4];
    const float* bnode = (const float*)d_in[5];
    const float* Wlc   = (const float*)d_in[6];
    const float* blc   = (const float*)d_in[7];
    const float* Wproj = (const float*)d_in[8];
    const float* bproj = (const float*)d_in[9];
    float* out = (float*)d_out;

    float* ws      = (float*)d_ws;
    float* glb     = ws + 0;         // B*F
    float* cK      = ws + 40960;     // B*F
    float* cK0     = ws + 81920;     // B
    float* m_part  = ws + 82432;     // B*4
    float* s_part  = ws + 83456;     // B*4
    float* cL      = ws + 84480;     // B*F
    float* cL0     = ws + 117248;    // B
    float* y_part8 = ws + 118272;    // B*4*2048 = 1048576 floats (4 MB)
    __half* xh     = (__half*)(ws + (2 << 20));  // 131 MB at 8 MB offset

    k_convmax<<<BB * FF / 4, 256, 0, stream>>>(x, xh, glb);
    k_prep   <<<BB, 256, 0, stream>>>(x, lc, glb, Wg, bg, Wnode, bnode, Wlc, blc, cK, cK0);
    k_attn   <<<BB * 4, 256, 0, stream>>>(xh, cK, cK0, y_part8, m_part, s_part);
    k_dense  <<<BB, 256, 0, stream>>>(y_part8, m_part, s_part, Wnode, bnode, Wproj, bproj, cL, cL0);
    k_logits <<<BB * 4, 256, 0, stream>>>(xh, cL, cL0, out);
}

// Round 6
// 196.087 us; speedup vs baseline: 1.1169x; 1.0296x over previous
//
#include <hip/hip_runtime.h>
#include <hip/hip_fp16.h>
#include <math.h>

#define BB 128
#define FF 256
#define NN 2000

typedef float f32x4 __attribute__((ext_vector_type(4)));
union H8 { f32x4 v; __half2 h[4]; };

// -------- K1: convert x -> fp16 AND row max (one wave per row, 16B ld/st) --------
__global__ __launch_bounds__(256) void k_convmax(const float* __restrict__ x,
                                                 __half* __restrict__ xh,
                                                 float* __restrict__ glb) {
    int row  = (blockIdx.x << 2) | (threadIdx.x >> 6);
    int lane = threadIdx.x & 63;
    const f32x4* src = (const f32x4*)(x + (size_t)row * NN);
    f32x4*       dst = (f32x4*)(xh + (size_t)row * NN);
    float m = -INFINITY;
    for (int i = lane; i < 250; i += 64) {
        f32x4 a = __builtin_nontemporal_load(src + 2 * i);
        f32x4 b = __builtin_nontemporal_load(src + 2 * i + 1);
        m = fmaxf(m, fmaxf(fmaxf(a.x, a.y), fmaxf(a.z, a.w)));
        m = fmaxf(m, fmaxf(fmaxf(b.x, b.y), fmaxf(b.z, b.w)));
        H8 o;
        o.h[0] = __floats2half2_rn(a.x, a.y);
        o.h[1] = __floats2half2_rn(a.z, a.w);
        o.h[2] = __floats2half2_rn(b.x, b.y);
        o.h[3] = __floats2half2_rn(b.z, b.w);
        dst[i] = o.v;
    }
#pragma unroll
    for (int off = 32; off; off >>= 1) m = fmaxf(m, __shfl_xor(m, off));
    if (!lane) glb[row] = m;
}

// -------- K2: per-batch dense prep -> cK[b,f], cK0[b] --------
__global__ __launch_bounds__(256) void k_prep(
    const float* __restrict__ x, const int* __restrict__ lc,
    const float* __restrict__ glb,
    const float* __restrict__ Wg, const float* __restrict__ bg,
    const float* __restrict__ Wnode, const float* __restrict__ bnode,
    const float* __restrict__ Wlc, const float* __restrict__ blc,
    float* __restrict__ cK, float* __restrict__ cK0)
{
    int b = blockIdx.x;
    int f = threadIdx.x;
    __shared__ float s_glb[FF], s_ctx[2 * FF], s_cQ[FF], s_red[FF];
    const float* xb = x + (size_t)b * FF * NN;
    s_glb[f] = glb[b * FF + f];
    int l0 = lc[2 * b], l1 = lc[2 * b + 1];
    s_ctx[f]      = xb[(size_t)f * NN + l0];
    s_ctx[FF + f] = xb[(size_t)f * NN + l1];
    __syncthreads();
    const float* wg = Wg + (size_t)f * FF;
    float q0 = 0, q1 = 0, q2 = 0, q3 = 0;
    for (int j = 0; j < FF; j += 4) {
        q0 = fmaf(wg[j],     s_glb[j],     q0);
        q1 = fmaf(wg[j + 1], s_glb[j + 1], q1);
        q2 = fmaf(wg[j + 2], s_glb[j + 2], q2);
        q3 = fmaf(wg[j + 3], s_glb[j + 3], q3);
    }
    const float* wl = Wlc + (size_t)f * 2 * FF;
    for (int j = 0; j < 2 * FF; j += 4) {
        q0 = fmaf(wl[j],     s_ctx[j],     q0);
        q1 = fmaf(wl[j + 1], s_ctx[j + 1], q1);
        q2 = fmaf(wl[j + 2], s_ctx[j + 2], q2);
        q3 = fmaf(wl[j + 3], s_ctx[j + 3], q3);
    }
    float cq = bg[f] + blc[f] + ((q0 + q1) + (q2 + q3));
    s_cQ[f]  = cq;
    s_red[f] = cq * bnode[f];
    __syncthreads();
    float c0 = 0, c1 = 0;
    for (int g = 0; g < FF; g += 2) {
        c0 = fmaf(s_cQ[g],     Wnode[(size_t)g * FF + f],       c0);
        c1 = fmaf(s_cQ[g + 1], Wnode[(size_t)(g + 1) * FF + f], c1);
    }
    cK[b * FF + f] = c0 + c1;
    for (int s = 128; s > 0; s >>= 1) {
        if (f < s) s_red[f] += s_red[f + s];
        __syncthreads();
    }
    if (f == 0) cK0[b] = s_red[0];
}

// -------- K3: fused u + stripe-softmax + stripe-ypool --------
// 512 threads = 8 waves x 32 f-rows; pass 2 transpose is wave-private (no barriers).
__global__ __launch_bounds__(512) void k_attn(
    const __half* __restrict__ xh,
    const float* __restrict__ cK, const float* __restrict__ cK0,
    float* __restrict__ y_part8, float* __restrict__ m_part,
    float* __restrict__ s_part)
{
    int b = blockIdx.x >> 2, s = blockIdx.x & 3;
    int tid = threadIdx.x, w = tid >> 6, lane = tid & 63;
    __shared__ float s_cK[FF];
    __shared__ float s_buf[8][512];
    __shared__ float s_p[512];
    __shared__ float s_red[8], s_red2[8];
    if (tid < FF) s_cK[tid] = cK[b * FF + tid];
    __syncthreads();

    int n0 = s << 9;
    int nbase = n0 + (lane << 3);
    bool valid = nbase < NN;
    int cb = lane << 3;
    const __half* rp = xh + (size_t)(b * FF + (w << 5)) * NN + nbase;

    // ---- pass 1: u partials over this wave's 32 f-rows (8-deep load batches) ----
    float a0 = 0, a1 = 0, a2 = 0, a3 = 0, a4 = 0, a5 = 0, a6 = 0, a7 = 0;
    if (valid) {
#pragma unroll
        for (int g = 0; g < 4; ++g) {
            f32x4 hv[8];
#pragma unroll
            for (int r = 0; r < 8; ++r)
                hv[r] = *(const f32x4*)(rp + (size_t)((g << 3) + r) * NN);
#pragma unroll
            for (int r = 0; r < 8; ++r) {
                H8 u; u.v = hv[r];
                float c = s_cK[(w << 5) + (g << 3) + r];
                float2 q0 = __half22float2(u.h[0]);
                float2 q1 = __half22float2(u.h[1]);
                float2 q2 = __half22float2(u.h[2]);
                float2 q3 = __half22float2(u.h[3]);
                a0 = fmaf(c, q0.x, a0); a1 = fmaf(c, q0.y, a1);
                a2 = fmaf(c, q1.x, a2); a3 = fmaf(c, q1.y, a3);
                a4 = fmaf(c, q2.x, a4); a5 = fmaf(c, q2.y, a5);
                a6 = fmaf(c, q3.x, a6); a7 = fmaf(c, q3.y, a7);
            }
        }
    }
    s_buf[w][cb + 0] = a0; s_buf[w][cb + 1] = a1;
    s_buf[w][cb + 2] = a2; s_buf[w][cb + 3] = a3;
    s_buf[w][cb + 4] = a4; s_buf[w][cb + 5] = a5;
    s_buf[w][cb + 6] = a6; s_buf[w][cb + 7] = a7;
    __syncthreads();

    // ---- stripe softmax (unnormalized): one column per thread ----
    const float scale = 0.0625f;
    float k0 = cK0[b];
    float u = 0.f;
#pragma unroll
    for (int ww = 0; ww < 8; ++ww) u += s_buf[ww][tid];
    float uu = (n0 + tid < NN) ? (u + k0) * scale : -INFINITY;
    float m = uu;
#pragma unroll
    for (int off = 32; off; off >>= 1) m = fmaxf(m, __shfl_xor(m, off));
    if (!lane) s_red[w] = m;
    __syncthreads();
    float M = s_red[0];
#pragma unroll
    for (int ww = 1; ww < 8; ++ww) M = fmaxf(M, s_red[ww]);
    float e = (uu > -INFINITY) ? __expf(uu - M) : 0.f;
    s_p[tid] = e;
    float ss = e;
#pragma unroll
    for (int off = 32; off; off >>= 1) ss += __shfl_xor(ss, off);
    if (!lane) s_red2[w] = ss;
    __syncthreads();
    if (!tid) {
        float S = 0.f;
#pragma unroll
        for (int ww = 0; ww < 8; ++ww) S += s_red2[ww];
        m_part[(b << 2) + s] = M;
        s_part[(b << 2) + s] = S;
    }

    // ---- pass 2: y8 partials, wave-private LDS transpose (no barriers) ----
    float4 pa = *(const float4*)&s_p[cb];
    float4 pc = *(const float4*)&s_p[cb + 4];
    float* yout = y_part8 + (size_t)((b << 2) + s) * 2048 + (w << 8);
    int row = lane >> 3, k = lane & 7;
#pragma unroll
    for (int g = 0; g < 4; ++g) {
        float part[8];
#pragma unroll
        for (int r = 0; r < 8; ++r) {
            float acc = 0.f;
            if (valid) {
                H8 u2; u2.v = *(const f32x4*)(rp + (size_t)((g << 3) + r) * NN);
                float2 q0 = __half22float2(u2.h[0]);
                float2 q1 = __half22float2(u2.h[1]);
                float2 q2 = __half22float2(u2.h[2]);
                float2 q3 = __half22float2(u2.h[3]);
                acc = fmaf(pa.x, q0.x, acc); acc = fmaf(pa.y, q0.y, acc);
                acc = fmaf(pa.z, q1.x, acc); acc = fmaf(pa.w, q1.y, acc);
                acc = fmaf(pc.x, q2.x, acc); acc = fmaf(pc.y, q2.y, acc);
                acc = fmaf(pc.z, q3.x, acc); acc = fmaf(pc.w, q3.y, acc);
            }
            part[r] = acc;
        }
#pragma unroll
        for (int r = 0; r < 8; ++r) s_buf[w][(r << 6) + lane] = part[r];
        const float* srcp = &s_buf[w][(row << 6) + (k << 3)];
        float4 aa = *(const float4*)srcp;
        float4 bb = *(const float4*)(srcp + 4);
        yout[(g << 6) + lane] =
            ((aa.x + aa.y) + (aa.z + aa.w)) + ((bb.x + bb.y) + (bb.z + bb.w));
    }
}

// -------- K4: combine stripe partials -> y -> dense chain -> cL, cL0 --------
__global__ __launch_bounds__(256) void k_dense(
    const float* __restrict__ y_part8, const float* __restrict__ m_part,
    const float* __restrict__ s_part,
    const float* __restrict__ Wnode, const float* __restrict__ bnode,
    const float* __restrict__ Wproj, const float* __restrict__ bproj,
    float* __restrict__ cL, float* __restrict__ cL0)
{
    int b = blockIdx.x;
    int f = threadIdx.x;
    int wid = f >> 6, lane = f & 63;
    __shared__ float s_y[FF], s_v[FF], s_red[4];

    float m0 = m_part[(b << 2)],     m1 = m_part[(b << 2) + 1];
    float m2 = m_part[(b << 2) + 2], m3 = m_part[(b << 2) + 3];
    float M = fmaxf(fmaxf(m0, m1), fmaxf(m2, m3));
    float w0 = __expf(m0 - M), w1 = __expf(m1 - M);
    float w2 = __expf(m2 - M), w3 = __expf(m3 - M);
    float S = s_part[(b << 2)] * w0 + s_part[(b << 2) + 1] * w1 +
              s_part[(b << 2) + 2] * w2 + s_part[(b << 2) + 3] * w3;
    float invS = 1.0f / S;
    const float* yb = y_part8 + ((size_t)b << 13);
    float wgt[4] = {w0, w1, w2, w3};
    float acc = 0.f;
#pragma unroll
    for (int s = 0; s < 4; ++s) {
        float4 aa = *(const float4*)(yb + (s << 11) + (f << 3));
        float4 bb = *(const float4*)(yb + (s << 11) + (f << 3) + 4);
        acc += wgt[s] * (((aa.x + aa.y) + (aa.z + aa.w)) + ((bb.x + bb.y) + (bb.z + bb.w)));
    }
    s_y[f] = acc * invS;
    __syncthreads();

    const float* wv = Wnode + (size_t)(FF + f) * FF;
    float a0 = 0, a1 = 0, a2 = 0, a3 = 0;
    for (int j = 0; j < FF; j += 4) {
        a0 = fmaf(wv[j],     s_y[j],     a0);
        a1 = fmaf(wv[j + 1], s_y[j + 1], a1);
        a2 = fmaf(wv[j + 2], s_y[j + 2], a2);
        a3 = fmaf(wv[j + 3], s_y[j + 3], a3);
    }
    s_v[f] = bnode[FF + f] + ((a0 + a1) + (a2 + a3));
    __syncthreads();
    const float* wp = Wproj + (size_t)f * FF;
    a0 = 0; a1 = 0; a2 = 0; a3 = 0;
    for (int j = 0; j < FF; j += 4) {
        a0 = fmaf(wp[j],     s_v[j],     a0);
        a1 = fmaf(wp[j + 1], s_v[j + 1], a1);
        a2 = fmaf(wp[j + 2], s_v[j + 2], a2);
        a3 = fmaf(wp[j + 3], s_v[j + 3], a3);
    }
    float nc2 = bproj[f] + ((a0 + a1) + (a2 + a3));
    __syncthreads();
    s_v[f] = nc2;
    __syncthreads();
    float c0 = 0, c1 = 0;
    for (int g = 0; g < FF; g += 2) {
        c0 = fmaf(s_v[g],     Wnode[(size_t)(2 * FF + g) * FF + f],     c0);
        c1 = fmaf(s_v[g + 1], Wnode[(size_t)(2 * FF + g + 1) * FF + f], c1);
    }
    cL[b * FF + f] = c0 + c1;
    float t = nc2 * bnode[2 * FF + f];
#pragma unroll
    for (int off = 32; off; off >>= 1) t += __shfl_xor(t, off);
    if (!lane) s_red[wid] = t;
    __syncthreads();
    if (!f) cL0[b] = s_red[0] + s_red[1] + s_red[2] + s_red[3];
}

// -------- K5: logits + tanh (512 threads = 8 waves x 32 f-rows) --------
__global__ __launch_bounds__(512) void k_logits(const __half* __restrict__ xh,
                                                const float* __restrict__ cL,
                                                const float* __restrict__ cL0,
                                                float* __restrict__ out)
{
    int b = blockIdx.x >> 2, s = blockIdx.x & 3;
    int tid = threadIdx.x, w = tid >> 6, lane = tid & 63;
    __shared__ float s_cL[FF];
    __shared__ float s_acc[8][512];
    if (tid < FF) s_cL[tid] = cL[b * FF + tid];
    __syncthreads();
    int n0 = s << 9;
    int nbase = n0 + (lane << 3);
    bool valid = nbase < NN;
    int cb = lane << 3;
    const __half* rp = xh + (size_t)(b * FF + (w << 5)) * NN + nbase;
    float a0 = 0, a1 = 0, a2 = 0, a3 = 0, a4 = 0, a5 = 0, a6 = 0, a7 = 0;
    if (valid) {
#pragma unroll
        for (int g = 0; g < 4; ++g) {
            f32x4 hv[8];
#pragma unroll
            for (int r = 0; r < 8; ++r)
                hv[r] = *(const f32x4*)(rp + (size_t)((g << 3) + r) * NN);
#pragma unroll
            for (int r = 0; r < 8; ++r) {
                H8 u; u.v = hv[r];
                float c = s_cL[(w << 5) + (g << 3) + r];
                float2 q0 = __half22float2(u.h[0]);
                float2 q1 = __half22float2(u.h[1]);
                float2 q2 = __half22float2(u.h[2]);
                float2 q3 = __half22float2(u.h[3]);
                a0 = fmaf(c, q0.x, a0); a1 = fmaf(c, q0.y, a1);
                a2 = fmaf(c, q1.x, a2); a3 = fmaf(c, q1.y, a3);
                a4 = fmaf(c, q2.x, a4); a5 = fmaf(c, q2.y, a5);
                a6 = fmaf(c, q3.x, a6); a7 = fmaf(c, q3.y, a7);
            }
        }
    }
    s_acc[w][cb + 0] = a0; s_acc[w][cb + 1] = a1;
    s_acc[w][cb + 2] = a2; s_acc[w][cb + 3] = a3;
    s_acc[w][cb + 4] = a4; s_acc[w][cb + 5] = a5;
    s_acc[w][cb + 6] = a6; s_acc[w][cb + 7] = a7;
    __syncthreads();
    int n = n0 + tid;
    if (n < NN) {
        float t = 0.f;
#pragma unroll
        for (int ww = 0; ww < 8; ++ww) t += s_acc[ww][tid];
        out[(size_t)b * NN + n] = tanhf((t + cL0[b]) * 0.0625f) * 10.f;
    }
}

extern "C" void kernel_launch(void* const* d_in, const int* in_sizes, int n_in,
                              void* d_out, int out_size, void* d_ws, size_t ws_size,
                              hipStream_t stream) {
    const float* x     = (const float*)d_in[0];
    const int*   lc    = (const int*)d_in[1];
    const float* Wg    = (const float*)d_in[2];
    const float* bg    = (const float*)d_in[3];
    const float* Wnode = (const float*)d_in[4];
    const float* bnode = (const float*)d_in[5];
    const float* Wlc   = (const float*)d_in[6];
    const float* blc   = (const float*)d_in[7];
    const float* Wproj = (const float*)d_in[8];
    const float* bproj = (const float*)d_in[9];
    float* out = (float*)d_out;

    float* ws      = (float*)d_ws;
    float* glb     = ws + 0;         // B*F
    float* cK      = ws + 40960;     // B*F
    float* cK0     = ws + 81920;     // B
    float* m_part  = ws + 82432;     // B*4
    float* s_part  = ws + 83456;     // B*4
    float* cL      = ws + 84480;     // B*F
    float* cL0     = ws + 117248;    // B
    float* y_part8 = ws + 118272;    // B*4*2048 floats (4 MB)
    __half* xh     = (__half*)(ws + (2 << 20));  // 131 MB at 8 MB offset

    k_convmax<<<BB * FF / 4, 256, 0, stream>>>(x, xh, glb);
    k_prep   <<<BB, 256, 0, stream>>>(x, lc, glb, Wg, bg, Wnode, bnode, Wlc, blc, cK, cK0);
    k_attn   <<<BB * 4, 512, 0, stream>>>(xh, cK, cK0, y_part8, m_part, s_part);
    k_dense  <<<BB, 256, 0, stream>>>(y_part8, m_part, s_part, Wnode, bnode, Wproj, bproj, cL, cL0);
    k_logits <<<BB * 4, 512, 0, stream>>>(xh, cL, cL0, out);
}

// Round 7
// 191.479 us; speedup vs baseline: 1.1437x; 1.0241x over previous
//
#include <hip/hip_runtime.h>
#include <hip/hip_fp16.h>
#include <math.h>

#define BB 128
#define FF 256
#define NN 2000
#define SW 8      // stripes per batch
#define SC 256    // cols per stripe  (NN=2000 -> stripe 7 partially valid; 2000%8==0)

typedef float f32x4 __attribute__((ext_vector_type(4)));
union H8 { f32x4 v; __half2 h[4]; };

// -------- K1: convert x -> fp16 AND row max (one wave per row, 16B ld/st) --------
__global__ __launch_bounds__(256) void k_convmax(const float* __restrict__ x,
                                                 __half* __restrict__ xh,
                                                 float* __restrict__ glb) {
    int row  = (blockIdx.x << 2) | (threadIdx.x >> 6);
    int lane = threadIdx.x & 63;
    const f32x4* src = (const f32x4*)(x + (size_t)row * NN);
    f32x4*       dst = (f32x4*)(xh + (size_t)row * NN);
    float m = -INFINITY;
    for (int i = lane; i < 250; i += 64) {
        f32x4 a = __builtin_nontemporal_load(src + 2 * i);
        f32x4 b = __builtin_nontemporal_load(src + 2 * i + 1);
        m = fmaxf(m, fmaxf(fmaxf(a.x, a.y), fmaxf(a.z, a.w)));
        m = fmaxf(m, fmaxf(fmaxf(b.x, b.y), fmaxf(b.z, b.w)));
        H8 o;
        o.h[0] = __floats2half2_rn(a.x, a.y);
        o.h[1] = __floats2half2_rn(a.z, a.w);
        o.h[2] = __floats2half2_rn(b.x, b.y);
        o.h[3] = __floats2half2_rn(b.z, b.w);
        dst[i] = o.v;
    }
#pragma unroll
    for (int off = 32; off; off >>= 1) m = fmaxf(m, __shfl_xor(m, off));
    if (!lane) glb[row] = m;
}

// -------- K2: per-batch dense prep -> cK[b,f], cK0[b] --------
__global__ __launch_bounds__(256) void k_prep(
    const float* __restrict__ x, const int* __restrict__ lc,
    const float* __restrict__ glb,
    const float* __restrict__ Wg, const float* __restrict__ bg,
    const float* __restrict__ Wnode, const float* __restrict__ bnode,
    const float* __restrict__ Wlc, const float* __restrict__ blc,
    float* __restrict__ cK, float* __restrict__ cK0)
{
    int b = blockIdx.x;
    int f = threadIdx.x;
    __shared__ float s_glb[FF], s_ctx[2 * FF], s_cQ[FF], s_red[FF];
    const float* xb = x + (size_t)b * FF * NN;
    s_glb[f] = glb[b * FF + f];
    int l0 = lc[2 * b], l1 = lc[2 * b + 1];
    s_ctx[f]      = xb[(size_t)f * NN + l0];
    s_ctx[FF + f] = xb[(size_t)f * NN + l1];
    __syncthreads();
    const float* wg = Wg + (size_t)f * FF;
    float q0 = 0, q1 = 0, q2 = 0, q3 = 0;
    for (int j = 0; j < FF; j += 4) {
        q0 = fmaf(wg[j],     s_glb[j],     q0);
        q1 = fmaf(wg[j + 1], s_glb[j + 1], q1);
        q2 = fmaf(wg[j + 2], s_glb[j + 2], q2);
        q3 = fmaf(wg[j + 3], s_glb[j + 3], q3);
    }
    const float* wl = Wlc + (size_t)f * 2 * FF;
    for (int j = 0; j < 2 * FF; j += 4) {
        q0 = fmaf(wl[j],     s_ctx[j],     q0);
        q1 = fmaf(wl[j + 1], s_ctx[j + 1], q1);
        q2 = fmaf(wl[j + 2], s_ctx[j + 2], q2);
        q3 = fmaf(wl[j + 3], s_ctx[j + 3], q3);
    }
    float cq = bg[f] + blc[f] + ((q0 + q1) + (q2 + q3));
    s_cQ[f]  = cq;
    s_red[f] = cq * bnode[f];
    __syncthreads();
    float c0 = 0, c1 = 0;
    for (int g = 0; g < FF; g += 2) {
        c0 = fmaf(s_cQ[g],     Wnode[(size_t)g * FF + f],       c0);
        c1 = fmaf(s_cQ[g + 1], Wnode[(size_t)(g + 1) * FF + f], c1);
    }
    cK[b * FF + f] = c0 + c1;
    for (int s = 128; s > 0; s >>= 1) {
        if (f < s) s_red[f] += s_red[f + s];
        __syncthreads();
    }
    if (f == 0) cK0[b] = s_red[0];
}

// -------- K3: fused attn, LDS-resident tile: xh read ONCE per stripe --------
// 1024 blocks x 512 thr. Stripe = 256 cols. Wave w owns rows [w*32, w*32+32).
// Lane: par = lane>>5 (row parity), chunk = lane&31 (8-col group).
__global__ __launch_bounds__(512) void k_attn(
    const __half* __restrict__ xh,
    const float* __restrict__ cK, const float* __restrict__ cK0,
    float* __restrict__ y_part, float* __restrict__ m_part,
    float* __restrict__ s_part)
{
    int b = blockIdx.x >> 3, st = blockIdx.x & 7;
    int tid = threadIdx.x, w = tid >> 6, lane = tid & 63;
    int par = lane >> 5, chunk = lane & 31;
    __shared__ __half tile[FF][SC];          // 131072 B
    __shared__ float s_u[8][SC];             // 8192 B
    __shared__ float s_p[SC];
    __shared__ float s_cK[FF];
    __shared__ float s_red[8], s_red2[8];
    if (tid < FF) s_cK[tid] = cK[b * FF + tid];
    __syncthreads();

    int colbase = (st << 8) + (chunk << 3);
    bool cvalid = colbase < NN;              // chunk fully valid or fully invalid
    const __half* base = xh + ((size_t)(b * FF) + (w << 5) + par) * NN + colbase;

    // ---- pass 1: load 16 rows x 16B once; stage to LDS; u-partials ----
    float up0 = 0, up1 = 0, up2 = 0, up3 = 0, up4 = 0, up5 = 0, up6 = 0, up7 = 0;
#pragma unroll
    for (int g = 0; g < 4; ++g) {
        f32x4 hv[4];
#pragma unroll
        for (int r = 0; r < 4; ++r) {
            if (cvalid) hv[r] = *(const f32x4*)(base + (size_t)((g << 3) + (r << 1)) * NN);
            else        hv[r] = (f32x4){0.f, 0.f, 0.f, 0.f};
        }
#pragma unroll
        for (int r = 0; r < 4; ++r) {
            int row = (w << 5) + par + (g << 3) + (r << 1);
            *(f32x4*)&tile[row][chunk << 3] = hv[r];
            H8 u; u.v = hv[r];
            float c = s_cK[row];
            float2 q0 = __half22float2(u.h[0]);
            float2 q1 = __half22float2(u.h[1]);
            float2 q2 = __half22float2(u.h[2]);
            float2 q3 = __half22float2(u.h[3]);
            up0 = fmaf(c, q0.x, up0); up1 = fmaf(c, q0.y, up1);
            up2 = fmaf(c, q1.x, up2); up3 = fmaf(c, q1.y, up3);
            up4 = fmaf(c, q2.x, up4); up5 = fmaf(c, q2.y, up5);
            up6 = fmaf(c, q3.x, up6); up7 = fmaf(c, q3.y, up7);
        }
    }
    // combine row-parities (lane <-> lane^32), then par==0 lanes write s_u
    up0 += __shfl_xor(up0, 32); up1 += __shfl_xor(up1, 32);
    up2 += __shfl_xor(up2, 32); up3 += __shfl_xor(up3, 32);
    up4 += __shfl_xor(up4, 32); up5 += __shfl_xor(up5, 32);
    up6 += __shfl_xor(up6, 32); up7 += __shfl_xor(up7, 32);
    if (!par) {
        f32x4 v0 = {up0, up1, up2, up3}, v1 = {up4, up5, up6, up7};
        *(f32x4*)&s_u[w][chunk << 3]       = v0;
        *(f32x4*)&s_u[w][(chunk << 3) + 4] = v1;
    }
    __syncthreads();

    // ---- stripe softmax over 256 cols (threads 0..255) ----
    const float scale = 0.0625f;
    float uu = -INFINITY;
    if (tid < SC) {
        int col = (st << 8) + tid;
        if (col < NN) {
            float usum = 0.f;
#pragma unroll
            for (int ww = 0; ww < 8; ++ww) usum += s_u[ww][tid];
            uu = (usum + cK0[b]) * scale;
        }
    }
    float m = uu;
#pragma unroll
    for (int off = 32; off; off >>= 1) m = fmaxf(m, __shfl_xor(m, off));
    if (!lane && w < 4) s_red[w] = m;
    __syncthreads();
    float M = fmaxf(fmaxf(s_red[0], s_red[1]), fmaxf(s_red[2], s_red[3]));
    float e = (uu > -INFINITY) ? __expf(uu - M) : 0.f;
    if (tid < SC) s_p[tid] = e;
    float ssum = e;
#pragma unroll
    for (int off = 32; off; off >>= 1) ssum += __shfl_xor(ssum, off);
    if (!lane && w < 4) s_red2[w] = ssum;
    __syncthreads();
    if (!tid) {
        m_part[(b << 3) + st] = M;
        s_part[(b << 3) + st] = s_red2[0] + s_red2[1] + s_red2[2] + s_red2[3];
    }

    // ---- pass 2: y from LDS tile (no global reads) ----
    f32x4 pv0 = *(const f32x4*)&s_p[chunk << 3];
    f32x4 pv1 = *(const f32x4*)&s_p[(chunk << 3) + 4];
    float acc[16];
#pragma unroll
    for (int k = 0; k < 16; ++k) {
        int row = (w << 5) + par + (k << 1);
        H8 u; u.v = *(const f32x4*)&tile[row][chunk << 3];
        float2 q0 = __half22float2(u.h[0]);
        float2 q1 = __half22float2(u.h[1]);
        float2 q2 = __half22float2(u.h[2]);
        float2 q3 = __half22float2(u.h[3]);
        float a = 0.f;
        a = fmaf(pv0.x, q0.x, a); a = fmaf(pv0.y, q0.y, a);
        a = fmaf(pv0.z, q1.x, a); a = fmaf(pv0.w, q1.y, a);
        a = fmaf(pv1.x, q2.x, a); a = fmaf(pv1.y, q2.y, a);
        a = fmaf(pv1.z, q3.x, a); a = fmaf(pv1.w, q3.y, a);
        acc[k] = a;
    }
    __syncthreads();   // all tile reads done; reuse tile as float scratch
    float* tbuf = (float*)&tile[0][0];
#pragma unroll
    for (int k = 0; k < 16; ++k)
        tbuf[(w << 10) + ((par + (k << 1)) << 5) + chunk] = acc[k];
    __syncthreads();
    {
        int row = tid >> 1, half = tid & 1;
        const float* src = tbuf + ((row >> 5) << 10) + ((row & 31) << 5) + (half << 4);
        f32x4 a0 = *(const f32x4*)src;
        f32x4 a1 = *(const f32x4*)(src + 4);
        f32x4 a2 = *(const f32x4*)(src + 8);
        f32x4 a3 = *(const f32x4*)(src + 12);
        float sm = ((a0.x + a0.y) + (a0.z + a0.w)) + ((a1.x + a1.y) + (a1.z + a1.w)) +
                   ((a2.x + a2.y) + (a2.z + a2.w)) + ((a3.x + a3.y) + (a3.z + a3.w));
        sm += __shfl_xor(sm, 1);
        if (!half) y_part[(size_t)((b << 3) + st) * FF + row] = sm;
    }
}

// -------- K4: combine 8 stripe partials -> y -> dense chain -> cL, cL0 --------
__global__ __launch_bounds__(256) void k_dense(
    const float* __restrict__ y_part, const float* __restrict__ m_part,
    const float* __restrict__ s_part,
    const float* __restrict__ Wnode, const float* __restrict__ bnode,
    const float* __restrict__ Wproj, const float* __restrict__ bproj,
    float* __restrict__ cL, float* __restrict__ cL0)
{
    int b = blockIdx.x;
    int f = threadIdx.x;
    int wid = f >> 6, lane = f & 63;
    __shared__ float s_y[FF], s_v[FF], s_red[4];

    float M = -INFINITY;
#pragma unroll
    for (int s = 0; s < 8; ++s) M = fmaxf(M, m_part[(b << 3) + s]);
    float S = 0.f, wgt[8];
#pragma unroll
    for (int s = 0; s < 8; ++s) {
        wgt[s] = __expf(m_part[(b << 3) + s] - M);
        S = fmaf(wgt[s], s_part[(b << 3) + s], S);
    }
    float invS = 1.0f / S;
    float acc = 0.f;
#pragma unroll
    for (int s = 0; s < 8; ++s)
        acc = fmaf(wgt[s], y_part[(size_t)((b << 3) + s) * FF + f], acc);
    s_y[f] = acc * invS;
    __syncthreads();

    const float* wv = Wnode + (size_t)(FF + f) * FF;
    float a0 = 0, a1 = 0, a2 = 0, a3 = 0;
    for (int j = 0; j < FF; j += 4) {
        a0 = fmaf(wv[j],     s_y[j],     a0);
        a1 = fmaf(wv[j + 1], s_y[j + 1], a1);
        a2 = fmaf(wv[j + 2], s_y[j + 2], a2);
        a3 = fmaf(wv[j + 3], s_y[j + 3], a3);
    }
    s_v[f] = bnode[FF + f] + ((a0 + a1) + (a2 + a3));
    __syncthreads();
    const float* wp = Wproj + (size_t)f * FF;
    a0 = 0; a1 = 0; a2 = 0; a3 = 0;
    for (int j = 0; j < FF; j += 4) {
        a0 = fmaf(wp[j],     s_v[j],     a0);
        a1 = fmaf(wp[j + 1], s_v[j + 1], a1);
        a2 = fmaf(wp[j + 2], s_v[j + 2], a2);
        a3 = fmaf(wp[j + 3], s_v[j + 3], a3);
    }
    float nc2 = bproj[f] + ((a0 + a1) + (a2 + a3));
    __syncthreads();
    s_v[f] = nc2;
    __syncthreads();
    float c0 = 0, c1 = 0;
    for (int g = 0; g < FF; g += 2) {
        c0 = fmaf(s_v[g],     Wnode[(size_t)(2 * FF + g) * FF + f],     c0);
        c1 = fmaf(s_v[g + 1], Wnode[(size_t)(2 * FF + g + 1) * FF + f], c1);
    }
    cL[b * FF + f] = c0 + c1;
    float t = nc2 * bnode[2 * FF + f];
#pragma unroll
    for (int off = 32; off; off >>= 1) t += __shfl_xor(t, off);
    if (!lane) s_red[wid] = t;
    __syncthreads();
    if (!f) cL0[b] = s_red[0] + s_red[1] + s_red[2] + s_red[3];
}

// -------- K5: logits + tanh (1024 blocks x 512 thr, 256-col stripes) --------
__global__ __launch_bounds__(512) void k_logits(const __half* __restrict__ xh,
                                                const float* __restrict__ cL,
                                                const float* __restrict__ cL0,
                                                float* __restrict__ out)
{
    int b = blockIdx.x >> 3, st = blockIdx.x & 7;
    int tid = threadIdx.x, w = tid >> 6, lane = tid & 63;
    int par = lane >> 5, chunk = lane & 31;
    __shared__ float s_cL[FF];
    __shared__ float s_acc[8][SC];
    if (tid < FF) s_cL[tid] = cL[b * FF + tid];
    __syncthreads();

    int colbase = (st << 8) + (chunk << 3);
    bool cvalid = colbase < NN;
    const __half* base = xh + ((size_t)(b * FF) + (w << 5) + par) * NN + colbase;
    float up0 = 0, up1 = 0, up2 = 0, up3 = 0, up4 = 0, up5 = 0, up6 = 0, up7 = 0;
    if (cvalid) {
#pragma unroll
        for (int g = 0; g < 4; ++g) {
            f32x4 hv[4];
#pragma unroll
            for (int r = 0; r < 4; ++r)
                hv[r] = *(const f32x4*)(base + (size_t)((g << 3) + (r << 1)) * NN);
#pragma unroll
            for (int r = 0; r < 4; ++r) {
                int row = (w << 5) + par + (g << 3) + (r << 1);
                H8 u; u.v = hv[r];
                float c = s_cL[row];
                float2 q0 = __half22float2(u.h[0]);
                float2 q1 = __half22float2(u.h[1]);
                float2 q2 = __half22float2(u.h[2]);
                float2 q3 = __half22float2(u.h[3]);
                up0 = fmaf(c, q0.x, up0); up1 = fmaf(c, q0.y, up1);
                up2 = fmaf(c, q1.x, up2); up3 = fmaf(c, q1.y, up3);
                up4 = fmaf(c, q2.x, up4); up5 = fmaf(c, q2.y, up5);
                up6 = fmaf(c, q3.x, up6); up7 = fmaf(c, q3.y, up7);
            }
        }
    }
    up0 += __shfl_xor(up0, 32); up1 += __shfl_xor(up1, 32);
    up2 += __shfl_xor(up2, 32); up3 += __shfl_xor(up3, 32);
    up4 += __shfl_xor(up4, 32); up5 += __shfl_xor(up5, 32);
    up6 += __shfl_xor(up6, 32); up7 += __shfl_xor(up7, 32);
    if (!par) {
        f32x4 v0 = {up0, up1, up2, up3}, v1 = {up4, up5, up6, up7};
        *(f32x4*)&s_acc[w][chunk << 3]       = v0;
        *(f32x4*)&s_acc[w][(chunk << 3) + 4] = v1;
    }
    __syncthreads();
    if (tid < SC) {
        int col = (st << 8) + tid;
        if (col < NN) {
            float t = 0.f;
#pragma unroll
            for (int ww = 0; ww < 8; ++ww) t += s_acc[ww][tid];
            out[(size_t)b * NN + col] = tanhf((t + cL0[b]) * 0.0625f) * 10.f;
        }
    }
}

extern "C" void kernel_launch(void* const* d_in, const int* in_sizes, int n_in,
                              void* d_out, int out_size, void* d_ws, size_t ws_size,
                              hipStream_t stream) {
    const float* x     = (const float*)d_in[0];
    const int*   lc    = (const int*)d_in[1];
    const float* Wg    = (const float*)d_in[2];
    const float* bg    = (const float*)d_in[3];
    const float* Wnode = (const float*)d_in[4];
    const float* bnode = (const float*)d_in[5];
    const float* Wlc   = (const float*)d_in[6];
    const float* blc   = (const float*)d_in[7];
    const float* Wproj = (const float*)d_in[8];
    const float* bproj = (const float*)d_in[9];
    float* out = (float*)d_out;

    float* ws     = (float*)d_ws;
    float* glb    = ws + 0;          // B*F
    float* cK     = ws + 40960;      // B*F
    float* cK0    = ws + 81920;      // B
    float* m_part = ws + 82944;      // B*8
    float* s_part = ws + 84992;      // B*8
    float* cL     = ws + 87040;      // B*F
    float* cL0    = ws + 120832;     // B
    float* y_part = ws + 121856;     // B*8*F = 262144 floats
    __half* xh    = (__half*)(ws + (2 << 20));  // 131 MB at 8 MB offset

    k_convmax<<<BB * FF / 4, 256, 0, stream>>>(x, xh, glb);
    k_prep   <<<BB, 256, 0, stream>>>(x, lc, glb, Wg, bg, Wnode, bnode, Wlc, blc, cK, cK0);
    k_attn   <<<BB * SW, 512, 0, stream>>>(xh, cK, cK0, y_part, m_part, s_part);
    k_dense  <<<BB, 256, 0, stream>>>(y_part, m_part, s_part, Wnode, bnode, Wproj, bproj, cL, cL0);
    k_logits <<<BB * SW, 512, 0, stream>>>(xh, cL, cL0, out);
}